// Round 4
// baseline (34.897 us; speedup 1.0000x reference)
//
#include <hip/hip_runtime.h>

constexpr int Hc = 128, Wc = 128, Cc = 64;
constexpr int Qc = 512 * 512;

// ---------------------------------------------------------------------------
// Kernel 1: fold the unfold3 + (q_feat part of) matmul into a 3x3 conv,
// 64 -> 3 channels, over the 128x128 feature map. Output S[pix*4 + o]
// (padded to float4 per pixel for single-load gathers in kernel 2).
// ---------------------------------------------------------------------------
__global__ __launch_bounds__(256) void conv3x3_S(const float* __restrict__ feat,
                                                 const float* __restrict__ wgt,
                                                 float* __restrict__ S) {
    __shared__ float ws[576 * 3];
    for (int i = threadIdx.x; i < 576 * 3; i += 256) ws[i] = wgt[i];
    __syncthreads();

    int pix = blockIdx.x * 256 + threadIdx.x;   // grid sized exactly H*W
    int y = pix >> 7;
    int x = pix & 127;

    float a0 = 0.f, a1 = 0.f, a2 = 0.f;
    for (int c = 0; c < Cc; ++c) {
        const float* fc = feat + c * Hc * Wc;
        const float* wr = ws + c * 27;
#pragma unroll
        for (int di = 0; di < 3; ++di) {
            int yy = y + di - 1;
            bool yok = (unsigned)yy < (unsigned)Hc;
#pragma unroll
            for (int dj = 0; dj < 3; ++dj) {
                int xx = x + dj - 1;
                bool ok = yok && ((unsigned)xx < (unsigned)Wc);
                float v = ok ? fc[yy * Wc + xx] : 0.f;
                const float* wk = wr + (di * 3 + dj) * 3;
                a0 = fmaf(v, wk[0], a0);
                a1 = fmaf(v, wk[1], a1);
                a2 = fmaf(v, wk[2], a2);
            }
        }
    }
    float4 o;
    o.x = a0; o.y = a1; o.z = a2; o.w = 0.f;
    *reinterpret_cast<float4*>(S + pix * 4) = o;
}

// ---------------------------------------------------------------------------
// Kernel 2: per-query. 4 shifts -> nearest pixel -> gather S (16B, L2-hit),
// add the rel/rel_cell linear tail + bias, area-weighted (swapped) blend.
// ---------------------------------------------------------------------------
__global__ __launch_bounds__(256) void liif_query(const float* __restrict__ coord,
                                                  const float* __restrict__ cell,
                                                  const float* __restrict__ wgt,
                                                  const float* __restrict__ bias,
                                                  const float* __restrict__ S,
                                                  float* __restrict__ out) {
    int q = blockIdx.x * 256 + threadIdx.x;     // grid sized exactly Q

    float2 co = *reinterpret_cast<const float2*>(coord + q * 2);
    float2 ce = *reinterpret_cast<const float2*>(cell + q * 2);
    float rcx = ce.x * 128.0f;
    float rcy = ce.y * 128.0f;

    // tail weight rows 576..579 and bias (uniform, L1-broadcast)
    float wx0 = wgt[576 * 3 + 0], wx1 = wgt[576 * 3 + 1], wx2 = wgt[576 * 3 + 2];
    float wy0 = wgt[577 * 3 + 0], wy1 = wgt[577 * 3 + 1], wy2 = wgt[577 * 3 + 2];
    float wc0 = wgt[578 * 3 + 0], wc1 = wgt[578 * 3 + 1], wc2 = wgt[578 * 3 + 2];
    float wd0 = wgt[579 * 3 + 0], wd1 = wgt[579 * 3 + 1], wd2 = wgt[579 * 3 + 2];
    float b0 = bias[0], b1 = bias[1], b2 = bias[2];

    // double-computed constants cast to fp32 (match numpy float64 scalar math)
    constexpr float SHN = (float)(-1.0 / 128.0 + 1e-6);
    constexpr float SHP = (float)( 1.0 / 128.0 + 1e-6);
    constexpr float CLO = (float)(-1.0 + 1e-6);
    constexpr float CHI = (float)( 1.0 - 1e-6);

    float pr[4][3];
    float area[4];
#pragma unroll
    for (int s = 0; s < 4; ++s) {
        // s=0:(-1,-1) s=1:(-1,+1) s=2:(+1,-1) s=3:(+1,+1)  (vx,vy)
        float sx = (s < 2) ? SHN : SHP;
        float sy = (s & 1) ? SHP : SHN;
        float cx_ = fminf(fmaxf(co.x + sx, CLO), CHI);
        float cy_ = fminf(fmaxf(co.y + sy, CLO), CHI);
        int ih = (int)floorf((cx_ + 1.0f) * 64.0f);
        ih = min(max(ih, 0), 127);
        int iw = (int)floorf((cy_ + 1.0f) * 64.0f);
        iw = min(max(iw, 0), 127);
        float qx = -1.0f + (float)(2 * ih + 1) * (1.0f / 128.0f);  // exact
        float qy = -1.0f + (float)(2 * iw + 1) * (1.0f / 128.0f);  // exact
        float relx = (co.x - qx) * 128.0f;
        float rely = (co.y - qy) * 128.0f;

        float4 sv = *reinterpret_cast<const float4*>(S + (ih * 128 + iw) * 4);
        pr[s][0] = sv.x + relx * wx0 + rely * wy0 + rcx * wc0 + rcy * wd0 + b0;
        pr[s][1] = sv.y + relx * wx1 + rely * wy1 + rcx * wc1 + rcy * wd1 + b1;
        pr[s][2] = sv.z + relx * wx2 + rely * wy2 + rcx * wc2 + rcy * wd2 + b2;
        area[s] = fabsf(relx * rely) + 1e-9f;
    }

    float tot = area[0] + area[1] + area[2] + area[3];
    float inv = 1.0f / tot;
    // swapped-area weights: pred[i] * area[3-i]/tot
    float g0 = area[3] * inv, g1 = area[2] * inv, g2 = area[1] * inv, g3 = area[0] * inv;

    float o0 = pr[0][0] * g0 + pr[1][0] * g1 + pr[2][0] * g2 + pr[3][0] * g3;
    float o1 = pr[0][1] * g0 + pr[1][1] * g1 + pr[2][1] * g2 + pr[3][1] * g3;
    float o2 = pr[0][2] * g0 + pr[1][2] * g1 + pr[2][2] * g2 + pr[3][2] * g3;

    out[q * 3 + 0] = o0;
    out[q * 3 + 1] = o1;
    out[q * 3 + 2] = o2;
}

extern "C" void kernel_launch(void* const* d_in, const int* in_sizes, int n_in,
                              void* d_out, int out_size, void* d_ws, size_t ws_size,
                              hipStream_t stream) {
    const float* feat  = (const float*)d_in[0];  // (1,64,128,128)
    const float* coord = (const float*)d_in[1];  // (1,Q,2)
    const float* cell  = (const float*)d_in[2];  // (1,Q,2)
    const float* wgt   = (const float*)d_in[3];  // (580,3)
    const float* bias  = (const float*)d_in[4];  // (3,)
    float* out = (float*)d_out;                  // (1,Q,3) fp32
    float* S   = (float*)d_ws;                   // 128*128*4 floats = 256 KB

    conv3x3_S<<<(Hc * Wc) / 256, 256, 0, stream>>>(feat, wgt, S);
    liif_query<<<Qc / 256, 256, 0, stream>>>(coord, cell, wgt, bias, S, out);
}

// Round 5
// 34.876 us; speedup vs baseline: 1.0006x; 1.0006x over previous
//
#include <hip/hip_runtime.h>

constexpr int Hc = 128, Wc = 128, Cc = 64;
constexpr int Qc = 512 * 512;

// ---------------------------------------------------------------------------
// Kernel 1: fold the unfold3 + (q_feat part of) matmul into a 3x3 conv,
// 64 -> 3 channels, over the 128x128 feature map. Output S[pix*4 + o]
// (padded to float4 per pixel for single-load gathers in kernel 2).
// ---------------------------------------------------------------------------
__global__ __launch_bounds__(256) void conv3x3_S(const float* __restrict__ feat,
                                                 const float* __restrict__ wgt,
                                                 float* __restrict__ S) {
    __shared__ float ws[576 * 3];
    for (int i = threadIdx.x; i < 576 * 3; i += 256) ws[i] = wgt[i];
    __syncthreads();

    int pix = blockIdx.x * 256 + threadIdx.x;   // grid sized exactly H*W
    int y = pix >> 7;
    int x = pix & 127;

    float a0 = 0.f, a1 = 0.f, a2 = 0.f;
    for (int c = 0; c < Cc; ++c) {
        const float* fc = feat + c * Hc * Wc;
        const float* wr = ws + c * 27;
#pragma unroll
        for (int di = 0; di < 3; ++di) {
            int yy = y + di - 1;
            bool yok = (unsigned)yy < (unsigned)Hc;
#pragma unroll
            for (int dj = 0; dj < 3; ++dj) {
                int xx = x + dj - 1;
                bool ok = yok && ((unsigned)xx < (unsigned)Wc);
                float v = ok ? fc[yy * Wc + xx] : 0.f;
                const float* wk = wr + (di * 3 + dj) * 3;
                a0 = fmaf(v, wk[0], a0);
                a1 = fmaf(v, wk[1], a1);
                a2 = fmaf(v, wk[2], a2);
            }
        }
    }
    float4 o;
    o.x = a0; o.y = a1; o.z = a2; o.w = 0.f;
    *reinterpret_cast<float4*>(S + pix * 4) = o;
}

// ---------------------------------------------------------------------------
// Kernel 2: per-query. 4 shifts -> nearest pixel -> gather S (16B, L2-hit),
// add the rel/rel_cell linear tail + bias, area-weighted (swapped) blend.
// ---------------------------------------------------------------------------
__global__ __launch_bounds__(256) void liif_query(const float* __restrict__ coord,
                                                  const float* __restrict__ cell,
                                                  const float* __restrict__ wgt,
                                                  const float* __restrict__ bias,
                                                  const float* __restrict__ S,
                                                  float* __restrict__ out) {
    int q = blockIdx.x * 256 + threadIdx.x;     // grid sized exactly Q

    float2 co = *reinterpret_cast<const float2*>(coord + q * 2);
    float2 ce = *reinterpret_cast<const float2*>(cell + q * 2);
    float rcx = ce.x * 128.0f;
    float rcy = ce.y * 128.0f;

    // tail weight rows 576..579 and bias (uniform, L1-broadcast)
    float wx0 = wgt[576 * 3 + 0], wx1 = wgt[576 * 3 + 1], wx2 = wgt[576 * 3 + 2];
    float wy0 = wgt[577 * 3 + 0], wy1 = wgt[577 * 3 + 1], wy2 = wgt[577 * 3 + 2];
    float wc0 = wgt[578 * 3 + 0], wc1 = wgt[578 * 3 + 1], wc2 = wgt[578 * 3 + 2];
    float wd0 = wgt[579 * 3 + 0], wd1 = wgt[579 * 3 + 1], wd2 = wgt[579 * 3 + 2];
    float b0 = bias[0], b1 = bias[1], b2 = bias[2];

    // double-computed constants cast to fp32 (match numpy float64 scalar math)
    constexpr float SHN = (float)(-1.0 / 128.0 + 1e-6);
    constexpr float SHP = (float)( 1.0 / 128.0 + 1e-6);
    constexpr float CLO = (float)(-1.0 + 1e-6);
    constexpr float CHI = (float)( 1.0 - 1e-6);

    float pr[4][3];
    float area[4];
#pragma unroll
    for (int s = 0; s < 4; ++s) {
        // s=0:(-1,-1) s=1:(-1,+1) s=2:(+1,-1) s=3:(+1,+1)  (vx,vy)
        float sx = (s < 2) ? SHN : SHP;
        float sy = (s & 1) ? SHP : SHN;
        float cx_ = fminf(fmaxf(co.x + sx, CLO), CHI);
        float cy_ = fminf(fmaxf(co.y + sy, CLO), CHI);
        int ih = (int)floorf((cx_ + 1.0f) * 64.0f);
        ih = min(max(ih, 0), 127);
        int iw = (int)floorf((cy_ + 1.0f) * 64.0f);
        iw = min(max(iw, 0), 127);
        float qx = -1.0f + (float)(2 * ih + 1) * (1.0f / 128.0f);  // exact
        float qy = -1.0f + (float)(2 * iw + 1) * (1.0f / 128.0f);  // exact
        float relx = (co.x - qx) * 128.0f;
        float rely = (co.y - qy) * 128.0f;

        float4 sv = *reinterpret_cast<const float4*>(S + (ih * 128 + iw) * 4);
        pr[s][0] = sv.x + relx * wx0 + rely * wy0 + rcx * wc0 + rcy * wd0 + b0;
        pr[s][1] = sv.y + relx * wx1 + rely * wy1 + rcx * wc1 + rcy * wd1 + b1;
        pr[s][2] = sv.z + relx * wx2 + rely * wy2 + rcx * wc2 + rcy * wd2 + b2;
        area[s] = fabsf(relx * rely) + 1e-9f;
    }

    float tot = area[0] + area[1] + area[2] + area[3];
    float inv = 1.0f / tot;
    // swapped-area weights: pred[i] * area[3-i]/tot
    float g0 = area[3] * inv, g1 = area[2] * inv, g2 = area[1] * inv, g3 = area[0] * inv;

    float o0 = pr[0][0] * g0 + pr[1][0] * g1 + pr[2][0] * g2 + pr[3][0] * g3;
    float o1 = pr[0][1] * g0 + pr[1][1] * g1 + pr[2][1] * g2 + pr[3][1] * g3;
    float o2 = pr[0][2] * g0 + pr[1][2] * g1 + pr[2][2] * g2 + pr[3][2] * g3;

    out[q * 3 + 0] = o0;
    out[q * 3 + 1] = o1;
    out[q * 3 + 2] = o2;
}

extern "C" void kernel_launch(void* const* d_in, const int* in_sizes, int n_in,
                              void* d_out, int out_size, void* d_ws, size_t ws_size,
                              hipStream_t stream) {
    const float* feat  = (const float*)d_in[0];  // (1,64,128,128)
    const float* coord = (const float*)d_in[1];  // (1,Q,2)
    const float* cell  = (const float*)d_in[2];  // (1,Q,2)
    const float* wgt   = (const float*)d_in[3];  // (580,3)
    const float* bias  = (const float*)d_in[4];  // (3,)
    float* out = (float*)d_out;                  // (1,Q,3) fp32
    float* S   = (float*)d_ws;                   // 128*128*4 floats = 256 KB

    conv3x3_S<<<(Hc * Wc) / 256, 256, 0, stream>>>(feat, wgt, S);
    liif_query<<<Qc / 256, 256, 0, stream>>>(coord, cell, wgt, bias, S, out);
}

// Round 6
// 18.281 us; speedup vs baseline: 1.9089x; 1.9078x over previous
//
#include <hip/hip_runtime.h>

constexpr int Hc = 128, Wc = 128, Cc = 64;
constexpr int Qc = 512 * 512;

constexpr int PIX_PER_BLK = 32;   // pixels per block (one 32-wide x-strip)
constexpr int CGRP = 8;           // channel groups per block
constexpr int CPER = Cc / CGRP;   // 8 channels per group

// ---------------------------------------------------------------------------
// Kernel 1: 3x3 conv (64 -> 3 ch) over the 128x128 feature map, folded from
// unfold3 + matmul. Parallelized over pixels AND channel groups:
//   tid = cg*32 + px ; 512 blocks ; LDS tree-reduce over the 8 channel groups.
// Output S[pix*4 + o], padded to float4/pixel for single-load gathers in K2.
// ---------------------------------------------------------------------------
__global__ __launch_bounds__(256) void conv3x3_S(const float* __restrict__ feat,
                                                 const float* __restrict__ wgt,
                                                 float* __restrict__ S) {
    __shared__ float ws[576 * 3];
    for (int i = threadIdx.x; i < 576 * 3; i += 256) ws[i] = wgt[i];

    __shared__ float part[CGRP][PIX_PER_BLK][3];   // [8][32][3]

    int px = threadIdx.x & 31;        // pixel within the strip (coalesced x)
    int cg = threadIdx.x >> 5;        // channel group 0..7
    int pix = blockIdx.x * PIX_PER_BLK + px;
    int y = pix >> 7;
    int x = pix & 127;

    __syncthreads();                  // ws ready

    float a0 = 0.f, a1 = 0.f, a2 = 0.f;
    const int c0 = cg * CPER;
#pragma unroll
    for (int ci = 0; ci < CPER; ++ci) {
        int c = c0 + ci;
        const float* fc = feat + c * Hc * Wc;
        const float* wr = ws + c * 27;
#pragma unroll
        for (int di = 0; di < 3; ++di) {
            int yy = y + di - 1;
            bool yok = (unsigned)yy < (unsigned)Hc;
#pragma unroll
            for (int dj = 0; dj < 3; ++dj) {
                int xx = x + dj - 1;
                bool ok = yok && ((unsigned)xx < (unsigned)Wc);
                float v = ok ? fc[yy * Wc + xx] : 0.f;
                const float* wk = wr + (di * 3 + dj) * 3;
                a0 = fmaf(v, wk[0], a0);
                a1 = fmaf(v, wk[1], a1);
                a2 = fmaf(v, wk[2], a2);
            }
        }
    }

    part[cg][px][0] = a0;
    part[cg][px][1] = a1;
    part[cg][px][2] = a2;
    __syncthreads();

    // tree reduce over channel groups: 8 -> 4 -> 2 -> 1
#pragma unroll
    for (int step = CGRP / 2; step > 0; step >>= 1) {
        if (cg < step) {
            part[cg][px][0] += part[cg + step][px][0];
            part[cg][px][1] += part[cg + step][px][1];
            part[cg][px][2] += part[cg + step][px][2];
        }
        __syncthreads();
    }

    if (cg == 0) {
        float4 o;
        o.x = part[0][px][0];
        o.y = part[0][px][1];
        o.z = part[0][px][2];
        o.w = 0.f;
        *reinterpret_cast<float4*>(S + pix * 4) = o;   // 32 lanes, 512B coalesced
    }
}

// ---------------------------------------------------------------------------
// Kernel 2: per-query. 4 shifts -> nearest pixel -> gather S (16B, L2-hit),
// add the rel/rel_cell linear tail + bias, area-weighted (swapped) blend.
// ---------------------------------------------------------------------------
__global__ __launch_bounds__(256) void liif_query(const float* __restrict__ coord,
                                                  const float* __restrict__ cell,
                                                  const float* __restrict__ wgt,
                                                  const float* __restrict__ bias,
                                                  const float* __restrict__ S,
                                                  float* __restrict__ out) {
    int q = blockIdx.x * 256 + threadIdx.x;     // grid sized exactly Q

    float2 co = *reinterpret_cast<const float2*>(coord + q * 2);
    float2 ce = *reinterpret_cast<const float2*>(cell + q * 2);
    float rcx = ce.x * 128.0f;
    float rcy = ce.y * 128.0f;

    // tail weight rows 576..579 and bias (uniform, L1-broadcast)
    float wx0 = wgt[576 * 3 + 0], wx1 = wgt[576 * 3 + 1], wx2 = wgt[576 * 3 + 2];
    float wy0 = wgt[577 * 3 + 0], wy1 = wgt[577 * 3 + 1], wy2 = wgt[577 * 3 + 2];
    float wc0 = wgt[578 * 3 + 0], wc1 = wgt[578 * 3 + 1], wc2 = wgt[578 * 3 + 2];
    float wd0 = wgt[579 * 3 + 0], wd1 = wgt[579 * 3 + 1], wd2 = wgt[579 * 3 + 2];
    float b0 = bias[0], b1 = bias[1], b2 = bias[2];

    // double-computed constants cast to fp32 (match numpy float64 scalar math)
    constexpr float SHN = (float)(-1.0 / 128.0 + 1e-6);
    constexpr float SHP = (float)( 1.0 / 128.0 + 1e-6);
    constexpr float CLO = (float)(-1.0 + 1e-6);
    constexpr float CHI = (float)( 1.0 - 1e-6);

    float pr[4][3];
    float area[4];
#pragma unroll
    for (int s = 0; s < 4; ++s) {
        // s=0:(-1,-1) s=1:(-1,+1) s=2:(+1,-1) s=3:(+1,+1)  (vx,vy)
        float sx = (s < 2) ? SHN : SHP;
        float sy = (s & 1) ? SHP : SHN;
        float cx_ = fminf(fmaxf(co.x + sx, CLO), CHI);
        float cy_ = fminf(fmaxf(co.y + sy, CLO), CHI);
        int ih = (int)floorf((cx_ + 1.0f) * 64.0f);
        ih = min(max(ih, 0), 127);
        int iw = (int)floorf((cy_ + 1.0f) * 64.0f);
        iw = min(max(iw, 0), 127);
        float qx = -1.0f + (float)(2 * ih + 1) * (1.0f / 128.0f);  // exact
        float qy = -1.0f + (float)(2 * iw + 1) * (1.0f / 128.0f);  // exact
        float relx = (co.x - qx) * 128.0f;
        float rely = (co.y - qy) * 128.0f;

        float4 sv = *reinterpret_cast<const float4*>(S + (ih * 128 + iw) * 4);
        pr[s][0] = sv.x + relx * wx0 + rely * wy0 + rcx * wc0 + rcy * wd0 + b0;
        pr[s][1] = sv.y + relx * wx1 + rely * wy1 + rcx * wc1 + rcy * wd1 + b1;
        pr[s][2] = sv.z + relx * wx2 + rely * wy2 + rcx * wc2 + rcy * wd2 + b2;
        area[s] = fabsf(relx * rely) + 1e-9f;
    }

    float tot = area[0] + area[1] + area[2] + area[3];
    float inv = 1.0f / tot;
    // swapped-area weights: pred[i] * area[3-i]/tot
    float g0 = area[3] * inv, g1 = area[2] * inv, g2 = area[1] * inv, g3 = area[0] * inv;

    float o0 = pr[0][0] * g0 + pr[1][0] * g1 + pr[2][0] * g2 + pr[3][0] * g3;
    float o1 = pr[0][1] * g0 + pr[1][1] * g1 + pr[2][1] * g2 + pr[3][1] * g3;
    float o2 = pr[0][2] * g0 + pr[1][2] * g1 + pr[2][2] * g2 + pr[3][2] * g3;

    out[q * 3 + 0] = o0;
    out[q * 3 + 1] = o1;
    out[q * 3 + 2] = o2;
}

extern "C" void kernel_launch(void* const* d_in, const int* in_sizes, int n_in,
                              void* d_out, int out_size, void* d_ws, size_t ws_size,
                              hipStream_t stream) {
    const float* feat  = (const float*)d_in[0];  // (1,64,128,128)
    const float* coord = (const float*)d_in[1];  // (1,Q,2)
    const float* cell  = (const float*)d_in[2];  // (1,Q,2)
    const float* wgt   = (const float*)d_in[3];  // (580,3)
    const float* bias  = (const float*)d_in[4];  // (3,)
    float* out = (float*)d_out;                  // (1,Q,3) fp32
    float* S   = (float*)d_ws;                   // 128*128*4 floats = 256 KB

    conv3x3_S<<<(Hc * Wc) / PIX_PER_BLK, 256, 0, stream>>>(feat, wgt, S);
    liif_query<<<Qc / 256, 256, 0, stream>>>(coord, cell, wgt, bias, S, out);
}

// Round 7
// 16.336 us; speedup vs baseline: 2.1362x; 1.1191x over previous
//
#include <hip/hip_runtime.h>

constexpr int Hc = 128, Wc = 128, Cc = 64;
constexpr int Qc = 512 * 512;

constexpr int PIX_PER_BLK = 16;   // pixels per block (16-wide x-strip)
constexpr int CGRP = 16;          // channel groups per block
constexpr int CPER = Cc / CGRP;   // 4 channels per group

// ---------------------------------------------------------------------------
// Kernel 1: 3x3 conv (64 -> 3 ch) over the 128x128 feature map, folded from
// unfold3 + matmul. tid = cg*16 + px ; 1024 blocks (4/CU) ; LDS tree-reduce
// over the 16 channel groups. Output S[pix*4 + o] padded to float4/pixel.
// ---------------------------------------------------------------------------
__global__ __launch_bounds__(256) void conv3x3_S(const float* __restrict__ feat,
                                                 const float* __restrict__ wgt,
                                                 float* __restrict__ S) {
    __shared__ float ws[576 * 3];
    for (int i = threadIdx.x; i < 576 * 3; i += 256) ws[i] = wgt[i];

    __shared__ float part[CGRP][PIX_PER_BLK][3];   // [16][16][3]

    int px = threadIdx.x & (PIX_PER_BLK - 1);
    int cg = threadIdx.x >> 4;        // 0..15
    int pix = blockIdx.x * PIX_PER_BLK + px;
    int y = pix >> 7;
    int x = pix & 127;

    __syncthreads();                  // ws ready

    float a0 = 0.f, a1 = 0.f, a2 = 0.f;
    const int c0 = cg * CPER;
#pragma unroll
    for (int ci = 0; ci < CPER; ++ci) {
        int c = c0 + ci;
        const float* fc = feat + c * Hc * Wc;
        const float* wr = ws + c * 27;
#pragma unroll
        for (int di = 0; di < 3; ++di) {
            int yy = y + di - 1;
            bool yok = (unsigned)yy < (unsigned)Hc;
#pragma unroll
            for (int dj = 0; dj < 3; ++dj) {
                int xx = x + dj - 1;
                bool ok = yok && ((unsigned)xx < (unsigned)Wc);
                float v = ok ? fc[yy * Wc + xx] : 0.f;
                const float* wk = wr + (di * 3 + dj) * 3;
                a0 = fmaf(v, wk[0], a0);
                a1 = fmaf(v, wk[1], a1);
                a2 = fmaf(v, wk[2], a2);
            }
        }
    }

    part[cg][px][0] = a0;
    part[cg][px][1] = a1;
    part[cg][px][2] = a2;
    __syncthreads();

    // tree reduce over channel groups: 16 -> 8 -> 4 -> 2 -> 1
#pragma unroll
    for (int step = CGRP / 2; step > 0; step >>= 1) {
        if (cg < step) {
            part[cg][px][0] += part[cg + step][px][0];
            part[cg][px][1] += part[cg + step][px][1];
            part[cg][px][2] += part[cg + step][px][2];
        }
        __syncthreads();
    }

    if (cg == 0) {
        float4 o;
        o.x = part[0][px][0];
        o.y = part[0][px][1];
        o.z = part[0][px][2];
        o.w = 0.f;
        *reinterpret_cast<float4*>(S + pix * 4) = o;   // 16 lanes, 256B coalesced
    }
}

// ---------------------------------------------------------------------------
// Kernel 2: 2 queries per thread. 4 shifts -> nearest pixel -> gather S
// (16B, L2-hit), add the rel/rel_cell linear tail + bias, swapped-area blend.
// float4 input loads, float2 output stores; 8 gathers in flight per thread.
// ---------------------------------------------------------------------------
__global__ __launch_bounds__(256) void liif_query(const float* __restrict__ coord,
                                                  const float* __restrict__ cell,
                                                  const float* __restrict__ wgt,
                                                  const float* __restrict__ bias,
                                                  const float* __restrict__ S,
                                                  float* __restrict__ out) {
    int t = blockIdx.x * 256 + threadIdx.x;     // grid sized exactly Q/2
    int q0 = t * 2;

    float4 co = *reinterpret_cast<const float4*>(coord + q0 * 2);  // x0,y0,x1,y1
    float4 ce = *reinterpret_cast<const float4*>(cell + q0 * 2);

    // tail weight rows 576..579 and bias (uniform, scalar-cached)
    float wx0 = wgt[576 * 3 + 0], wx1 = wgt[576 * 3 + 1], wx2 = wgt[576 * 3 + 2];
    float wy0 = wgt[577 * 3 + 0], wy1 = wgt[577 * 3 + 1], wy2 = wgt[577 * 3 + 2];
    float wc0 = wgt[578 * 3 + 0], wc1 = wgt[578 * 3 + 1], wc2 = wgt[578 * 3 + 2];
    float wd0 = wgt[579 * 3 + 0], wd1 = wgt[579 * 3 + 1], wd2 = wgt[579 * 3 + 2];
    float b0 = bias[0], b1 = bias[1], b2 = bias[2];

    // double-computed constants cast to fp32 (match numpy float64 scalar math)
    constexpr float SHN = (float)(-1.0 / 128.0 + 1e-6);
    constexpr float SHP = (float)( 1.0 / 128.0 + 1e-6);
    constexpr float CLO = (float)(-1.0 + 1e-6);
    constexpr float CHI = (float)( 1.0 - 1e-6);

    float res[6];
#pragma unroll
    for (int k = 0; k < 2; ++k) {
        float cox = k ? co.z : co.x;
        float coy = k ? co.w : co.y;
        float rcx = (k ? ce.z : ce.x) * 128.0f;
        float rcy = (k ? ce.w : ce.y) * 128.0f;

        float pr[4][3];
        float area[4];
#pragma unroll
        for (int s = 0; s < 4; ++s) {
            // s=0:(-1,-1) s=1:(-1,+1) s=2:(+1,-1) s=3:(+1,+1)  (vx,vy)
            float sx = (s < 2) ? SHN : SHP;
            float sy = (s & 1) ? SHP : SHN;
            float cx_ = fminf(fmaxf(cox + sx, CLO), CHI);
            float cy_ = fminf(fmaxf(coy + sy, CLO), CHI);
            int ih = (int)floorf((cx_ + 1.0f) * 64.0f);
            ih = min(max(ih, 0), 127);
            int iw = (int)floorf((cy_ + 1.0f) * 64.0f);
            iw = min(max(iw, 0), 127);
            float qx = -1.0f + (float)(2 * ih + 1) * (1.0f / 128.0f);  // exact
            float qy = -1.0f + (float)(2 * iw + 1) * (1.0f / 128.0f);  // exact
            float relx = (cox - qx) * 128.0f;
            float rely = (coy - qy) * 128.0f;

            float4 sv = *reinterpret_cast<const float4*>(S + (ih * 128 + iw) * 4);
            pr[s][0] = sv.x + relx * wx0 + rely * wy0 + rcx * wc0 + rcy * wd0 + b0;
            pr[s][1] = sv.y + relx * wx1 + rely * wy1 + rcx * wc1 + rcy * wd1 + b1;
            pr[s][2] = sv.z + relx * wx2 + rely * wy2 + rcx * wc2 + rcy * wd2 + b2;
            area[s] = fabsf(relx * rely) + 1e-9f;
        }

        float tot = area[0] + area[1] + area[2] + area[3];
        float inv = 1.0f / tot;
        // swapped-area weights: pred[i] * area[3-i]/tot
        float g0 = area[3] * inv, g1 = area[2] * inv, g2 = area[1] * inv, g3 = area[0] * inv;

        res[k * 3 + 0] = pr[0][0] * g0 + pr[1][0] * g1 + pr[2][0] * g2 + pr[3][0] * g3;
        res[k * 3 + 1] = pr[0][1] * g0 + pr[1][1] * g1 + pr[2][1] * g2 + pr[3][1] * g3;
        res[k * 3 + 2] = pr[0][2] * g0 + pr[1][2] * g1 + pr[2][2] * g2 + pr[3][2] * g3;
    }

    float2* op = reinterpret_cast<float2*>(out + q0 * 3);  // 8B-aligned (24B/thread)
    op[0] = make_float2(res[0], res[1]);
    op[1] = make_float2(res[2], res[3]);
    op[2] = make_float2(res[4], res[5]);
}

extern "C" void kernel_launch(void* const* d_in, const int* in_sizes, int n_in,
                              void* d_out, int out_size, void* d_ws, size_t ws_size,
                              hipStream_t stream) {
    const float* feat  = (const float*)d_in[0];  // (1,64,128,128)
    const float* coord = (const float*)d_in[1];  // (1,Q,2)
    const float* cell  = (const float*)d_in[2];  // (1,Q,2)
    const float* wgt   = (const float*)d_in[3];  // (580,3)
    const float* bias  = (const float*)d_in[4];  // (3,)
    float* out = (float*)d_out;                  // (1,Q,3) fp32
    float* S   = (float*)d_ws;                   // 128*128*4 floats = 256 KB

    conv3x3_S<<<(Hc * Wc) / PIX_PER_BLK, 256, 0, stream>>>(feat, wgt, S);
    liif_query<<<Qc / 512, 256, 0, stream>>>(coord, cell, wgt, bias, S, out);
}